// Round 7
// baseline (118.679 us; speedup 1.0000x reference)
//
#include <hip/hip_runtime.h>
#include <math.h>

// TopLeftPool: p[b,c,i,j] = max_{h>=i, w>=j} x[b,c,h,w]  (reverse cummax H, then W)
//
// One BLOCK (8 waves, 512 threads) per 128x128 map; wave w owns the 16-row
// segment [16w, 16w+16), processed bottom-up as 8 ROW PAIRS:
//   lanes  0..31 (half 0) -> row 2pr,   lanes 32..63 (half 1) -> row 2pr+1.
// Each half-lane h = lane&31 covers cols {124-4h .. 127-4h} (float4, reversed
// so the W suffix-max is a lane-PREFIX-max confined to the 32-lane half:
// row_shr 1/2/4/8 + row_bcast15[mask 0xA] -- 5 DPP steps, no row_bcast31).
// One 64-lane DPP scan processes TWO rows at once; memory ops are 16B/lane
// (1KB/wave-instr, the measured-copy sweet spot).
//
// Cross-half H-carry: v_permlane32_swap_b32 (pure VALU). With both operands
// = S, the two results are S_lo and S_hi lane-matched in BOTH halves, so
// max(r.x, r.y) = max(S_row2pr, S_row2pr+1) directly.
//
// Phase 2: per-column segment totals via 4KB LDS + one barrier; fold
// segments below. Phase 3: fold + 16B non-temporal stores.

#define N_MAPS (16 * 256)
#define W 128
#define SEG 16
#define NWAVES 8
#define NPAIR (SEG / 2)

typedef float f32x4 __attribute__((ext_vector_type(4)));
typedef int   i32x2 __attribute__((ext_vector_type(2)));

// m = fmax(m, dpp_select(m)); invalid-source / masked-row lanes keep m
// (identity under max).
template <int CTRL, int ROW_MASK>
__device__ __forceinline__ float dpp_max(float m) {
    int t = __builtin_amdgcn_update_dpp(__float_as_int(m), __float_as_int(m),
                                        CTRL, ROW_MASK, 0xF, false);
    return fmaxf(m, __int_as_float(t));
}

__global__ __launch_bounds__(512, 8) void
TopLeftPool_54357106098212_kernel(const float* __restrict__ x,
                                  float* __restrict__ out) {
    __shared__ f32x4 totals[NWAVES][32];

    const int map  = (int)blockIdx.x;
    const int w    = (int)(threadIdx.x >> 6);   // wave id = segment id
    const int lane = (int)(threadIdx.x & 63);
    const int h    = lane & 31;                 // column-block id within half
    const int g    = lane >> 5;                 // 0 = even row, 1 = odd row

    // This lane's row offset within the pair is g; col block starts at 124-4h.
    const size_t base = (size_t)map * (W * W) + (size_t)(w * SEG + g) * W
                        + (size_t)(124 - 4 * h);
    const float* __restrict__ xp = x + base;
    float* __restrict__ op = out + base;

    f32x4 v[NPAIR];
    float c0 = -INFINITY, c1 = -INFINITY, c2 = -INFINITY, c3 = -INFINITY;

    // Bottom-up over row pairs; each iteration scans 2 rows with ONE DPP scan.
    #pragma unroll
    for (int pr = NPAIR - 1; pr >= 0; --pr) {
        const f32x4 d = *reinterpret_cast<const f32x4*>(xp + (size_t)pr * (2 * W));
        const float a0 = d.x, a1 = d.y, a2 = d.z, a3 = d.w;

        // Lane-local suffix over the 4 owned columns (ascending col order).
        const float s3 = a3;
        const float s2 = fmaxf(a2, s3);
        const float s1 = fmaxf(a1, s2);
        const float s0 = fmaxf(a0, s1);   // = lane max

        // Exclusive-prefix input: lanemax from lane-1; half-start lanes -> -inf.
        int sh = __builtin_amdgcn_update_dpp(
            __float_as_int(s0), __float_as_int(s0), 0x138 /*wave_shr:1*/,
            0xF, 0xF, false);
        float e = (h == 0) ? -INFINITY : __int_as_float(sh);

        // Inclusive prefix-max over each 32-lane half (both rows at once).
        e = dpp_max<0x111, 0xF>(e);   // row_shr:1
        e = dpp_max<0x112, 0xF>(e);   // row_shr:2
        e = dpp_max<0x114, 0xF>(e);   // row_shr:4
        e = dpp_max<0x118, 0xF>(e);   // row_shr:8
        e = dpp_max<0x142, 0xA>(e);   // row_bcast15 -> lanes 16-31 / 48-63

        // Row-suffix at this lane's 4 cols (own row).
        const float S0 = fmaxf(s0, e);
        const float S1 = fmaxf(s1, e);
        const float S2 = fmaxf(s2, e);
        const float S3 = fmaxf(s3, e);

        // Cross-half exchange: both results lane-matched; max(r.x,r.y) =
        // max over the two rows of the pair at this column.
        const i32x2 r0 = __builtin_amdgcn_permlane32_swap(
            __float_as_int(S0), __float_as_int(S0), false, false);
        const i32x2 r1 = __builtin_amdgcn_permlane32_swap(
            __float_as_int(S1), __float_as_int(S1), false, false);
        const i32x2 r2 = __builtin_amdgcn_permlane32_swap(
            __float_as_int(S2), __float_as_int(S2), false, false);
        const i32x2 r3 = __builtin_amdgcn_permlane32_swap(
            __float_as_int(S3), __float_as_int(S3), false, false);
        const float p0 = fmaxf(__int_as_float(r0.x), __int_as_float(r0.y));
        const float p1 = fmaxf(__int_as_float(r1.x), __int_as_float(r1.y));
        const float p2 = fmaxf(__int_as_float(r2.x), __int_as_float(r2.y));
        const float p3 = fmaxf(__int_as_float(r3.x), __int_as_float(r3.y));

        // q = pooled value of OWN row given carry c (c = pooled rows >= 2pr+2):
        //   half1 (row 2pr+1): q = max(S, c)           -> its output
        //   half0 (row 2pr):   output = c' = max(q, p) -> pooled row 2pr
        const float q0 = fmaxf(S0, c0);
        const float q1 = fmaxf(S1, c1);
        const float q2 = fmaxf(S2, c2);
        const float q3 = fmaxf(S3, c3);
        c0 = fmaxf(q0, p0);   // new carry = max(S_even, S_odd, c) (both halves)
        c1 = fmaxf(q1, p1);
        c2 = fmaxf(q2, p2);
        c3 = fmaxf(q3, p3);

        f32x4 o;
        o.x = g ? q0 : c0;
        o.y = g ? q1 : c1;
        o.z = g ? q2 : c2;
        o.w = g ? q3 : c3;
        v[pr] = o;
    }

    // Phase 2: per-column segment totals (identical in both halves).
    if (lane < 32) totals[w][h] = (f32x4){c0, c1, c2, c3};
    __syncthreads();

    float f0 = -INFINITY, f1 = -INFINITY, f2 = -INFINITY, f3 = -INFINITY;
    for (int w2 = w + 1; w2 < NWAVES; ++w2) {   // wave-uniform trip count
        const f32x4 t = totals[w2][h];
        f0 = fmaxf(f0, t.x);
        f1 = fmaxf(f1, t.y);
        f2 = fmaxf(f2, t.z);
        f3 = fmaxf(f3, t.w);
    }

    // Phase 3: fold segments below, stream out non-temporal 16B stores.
    #pragma unroll
    for (int pr = 0; pr < NPAIR; ++pr) {
        f32x4 o;
        o.x = fmaxf(v[pr].x, f0);
        o.y = fmaxf(v[pr].y, f1);
        o.z = fmaxf(v[pr].z, f2);
        o.w = fmaxf(v[pr].w, f3);
        __builtin_nontemporal_store(
            o, reinterpret_cast<f32x4*>(op + (size_t)pr * (2 * W)));
    }
}

extern "C" void kernel_launch(void* const* d_in, const int* in_sizes, int n_in,
                              void* d_out, int out_size, void* d_ws, size_t ws_size,
                              hipStream_t stream) {
    (void)in_sizes; (void)n_in; (void)out_size; (void)d_ws; (void)ws_size;
    const float* x = (const float*)d_in[0];
    float* out = (float*)d_out;

    // One block (8 waves) per map.
    dim3 grid(N_MAPS);
    dim3 block(64 * NWAVES);
    hipLaunchKernelGGL(TopLeftPool_54357106098212_kernel, grid, block, 0, stream,
                       x, out);
}

// Round 8
// 86.184 us; speedup vs baseline: 1.3770x; 1.3770x over previous
//
#include <hip/hip_runtime.h>
#include <math.h>

// TopLeftPool: p[b,c,i,j] = max_{h>=i, w>=j} x[b,c,h,w]  (reverse cummax H, then W)
//
// One BLOCK (16 waves, 1024 threads) per 128x128 map; wave w owns the 8-row
// segment [8w, 8w+8), processed bottom-up as 4 ROW PAIRS:
//   lanes  0..31 (half 0) -> row 2pr,   lanes 32..63 (half 1) -> row 2pr+1.
// Each half-lane h = lane&31 covers cols {124-4h .. 127-4h} (float4, reversed
// so the W suffix-max is a lane-PREFIX-max confined to the 32-lane half:
// row_shr 1/2/4/8 + row_bcast15[mask 0xA]). One 64-lane DPP scan serves two
// rows; memory ops are 16 B/lane.
//
// Cross-half H-carry: v_permlane32_swap_b32 (pure VALU); with both operands
// = S the two results are S_lo/S_hi lane-matched in both halves, so
// max(r.x, r.y) = max over the pair's two rows at this column.
//
// R7 lesson: SEG=16 + float4 spilled 3 f32x4/thread to scratch (WRITE_SIZE
// 262->360 MB, 11/8 amplification). SEG=8 halves held state (v[4] = 16 regs,
// ~40 total) -> fits the 64-VGPR cap of 8 waves/SIMD with no spill.

#define N_MAPS (16 * 256)
#define W 128
#define SEG 8
#define NWAVES 16
#define NPAIR (SEG / 2)

typedef float f32x4 __attribute__((ext_vector_type(4)));
typedef int   i32x2 __attribute__((ext_vector_type(2)));

// m = fmax(m, dpp_select(m)); invalid-source / masked-row lanes keep m
// (identity under max).
template <int CTRL, int ROW_MASK>
__device__ __forceinline__ float dpp_max(float m) {
    int t = __builtin_amdgcn_update_dpp(__float_as_int(m), __float_as_int(m),
                                        CTRL, ROW_MASK, 0xF, false);
    return fmaxf(m, __int_as_float(t));
}

__global__ __launch_bounds__(1024, 8) void
TopLeftPool_54357106098212_kernel(const float* __restrict__ x,
                                  float* __restrict__ out) {
    __shared__ f32x4 totals[NWAVES][32];

    const int map  = (int)blockIdx.x;
    const int w    = (int)(threadIdx.x >> 6);   // wave id = segment id
    const int lane = (int)(threadIdx.x & 63);
    const int h    = lane & 31;                 // column-block id within half
    const int g    = lane >> 5;                 // 0 = even row, 1 = odd row

    const size_t base = (size_t)map * (W * W) + (size_t)(w * SEG + g) * W
                        + (size_t)(124 - 4 * h);
    const float* __restrict__ xp = x + base;
    float* __restrict__ op = out + base;

    f32x4 v[NPAIR];
    float c0 = -INFINITY, c1 = -INFINITY, c2 = -INFINITY, c3 = -INFINITY;

    // Bottom-up over row pairs; each iteration scans 2 rows with ONE DPP scan.
    #pragma unroll
    for (int pr = NPAIR - 1; pr >= 0; --pr) {
        const f32x4 d = *reinterpret_cast<const f32x4*>(xp + (size_t)pr * (2 * W));

        // Lane-local suffix over the 4 owned columns (ascending col order).
        const float s3 = d.w;
        const float s2 = fmaxf(d.z, s3);
        const float s1 = fmaxf(d.y, s2);
        const float s0 = fmaxf(d.x, s1);   // = lane max

        // Exclusive-prefix input: lanemax from lane-1; half-start lanes -> -inf.
        int shv = __builtin_amdgcn_update_dpp(
            __float_as_int(s0), __float_as_int(s0), 0x138 /*wave_shr:1*/,
            0xF, 0xF, false);
        float e = (h == 0) ? -INFINITY : __int_as_float(shv);

        // Inclusive prefix-max over each 32-lane half (both rows at once).
        e = dpp_max<0x111, 0xF>(e);   // row_shr:1
        e = dpp_max<0x112, 0xF>(e);   // row_shr:2
        e = dpp_max<0x114, 0xF>(e);   // row_shr:4
        e = dpp_max<0x118, 0xF>(e);   // row_shr:8
        e = dpp_max<0x142, 0xA>(e);   // row_bcast15 -> lanes 16-31 / 48-63

        // Row-suffix at this lane's 4 cols (own row).
        const float S0 = fmaxf(s0, e);
        const float S1 = fmaxf(s1, e);
        const float S2 = fmaxf(s2, e);
        const float S3 = fmaxf(s3, e);

        // Cross-half exchange (pure VALU); p = max over the pair's two rows.
        const i32x2 r0 = __builtin_amdgcn_permlane32_swap(
            __float_as_int(S0), __float_as_int(S0), false, false);
        const i32x2 r1 = __builtin_amdgcn_permlane32_swap(
            __float_as_int(S1), __float_as_int(S1), false, false);
        const i32x2 r2 = __builtin_amdgcn_permlane32_swap(
            __float_as_int(S2), __float_as_int(S2), false, false);
        const i32x2 r3 = __builtin_amdgcn_permlane32_swap(
            __float_as_int(S3), __float_as_int(S3), false, false);
        const float p0 = fmaxf(__int_as_float(r0.x), __int_as_float(r0.y));
        const float p1 = fmaxf(__int_as_float(r1.x), __int_as_float(r1.y));
        const float p2 = fmaxf(__int_as_float(r2.x), __int_as_float(r2.y));
        const float p3 = fmaxf(__int_as_float(r3.x), __int_as_float(r3.y));

        // q = pooled own row given carry c (c = pooled rows >= 2pr+2):
        //   half1 (row 2pr+1): output q = max(S, c)
        //   half0 (row 2pr):   output c' = max(q, p) = pooled row 2pr
        const float q0 = fmaxf(S0, c0);
        const float q1 = fmaxf(S1, c1);
        const float q2 = fmaxf(S2, c2);
        const float q3 = fmaxf(S3, c3);
        c0 = fmaxf(q0, p0);
        c1 = fmaxf(q1, p1);
        c2 = fmaxf(q2, p2);
        c3 = fmaxf(q3, p3);

        f32x4 o;
        o.x = g ? q0 : c0;
        o.y = g ? q1 : c1;
        o.z = g ? q2 : c2;
        o.w = g ? q3 : c3;
        v[pr] = o;
    }

    // Phase 2: per-column segment totals (identical in both halves).
    if (lane < 32) totals[w][h] = (f32x4){c0, c1, c2, c3};
    __syncthreads();

    float f0 = -INFINITY, f1 = -INFINITY, f2 = -INFINITY, f3 = -INFINITY;
    for (int w2 = w + 1; w2 < NWAVES; ++w2) {   // wave-uniform trip count
        const f32x4 t = totals[w2][h];
        f0 = fmaxf(f0, t.x);
        f1 = fmaxf(f1, t.y);
        f2 = fmaxf(f2, t.z);
        f3 = fmaxf(f3, t.w);
    }

    // Phase 3: fold segments below, stream out non-temporal 16 B stores.
    #pragma unroll
    for (int pr = 0; pr < NPAIR; ++pr) {
        f32x4 o;
        o.x = fmaxf(v[pr].x, f0);
        o.y = fmaxf(v[pr].y, f1);
        o.z = fmaxf(v[pr].z, f2);
        o.w = fmaxf(v[pr].w, f3);
        __builtin_nontemporal_store(
            o, reinterpret_cast<f32x4*>(op + (size_t)pr * (2 * W)));
    }
}

extern "C" void kernel_launch(void* const* d_in, const int* in_sizes, int n_in,
                              void* d_out, int out_size, void* d_ws, size_t ws_size,
                              hipStream_t stream) {
    (void)in_sizes; (void)n_in; (void)out_size; (void)d_ws; (void)ws_size;
    const float* x = (const float*)d_in[0];
    float* out = (float*)d_out;

    // One block (16 waves) per map.
    dim3 grid(N_MAPS);
    dim3 block(64 * NWAVES);
    hipLaunchKernelGGL(TopLeftPool_54357106098212_kernel, grid, block, 0, stream,
                       x, out);
}

// Round 9
// 83.047 us; speedup vs baseline: 1.4291x; 1.0378x over previous
//
#include <hip/hip_runtime.h>
#include <math.h>

// TopLeftPool: p[b,c,i,j] = max_{h>=i, w>=j} x[b,c,h,w]  (reverse cummax H, then W)
//
// PERSISTENT-BLOCK version of the R6 structure (best: 82.5 us).
// 1024 blocks x 512 threads = exactly 4 blocks/CU, all resident; each block
// processes 4 maps in a loop (map = blockIdx.x + m*1024). Within each wave,
// the nt stores of map m overlap the loads of map m+1 -> continuous
// read/write mix at the HBM controller, and the cold-load ramp is paid per
// block (1024x) instead of per map (4096x).
//
// Per map: wave w owns 16-row segment [16w,16w+16). Issue all 16 float2
// row-loads, DPP-scan each row (reversed col->lane mapping makes the W
// suffix-max a lane prefix-max; pure VALU), fold segment H-carry in place.
// Exchange per-column segment totals via ping-pong LDS (one barrier per
// map; iteration m+2's writes to buffer p are ordered after iteration
// m+1's barrier, so no WAR race), fold segments below, stream 16 coalesced
// non-temporal 512 B stores.

#define N_MAPS (16 * 256)
#define W 128
#define SEG 16
#define NWAVES 8
#define NBLOCKS 1024
#define MPB (N_MAPS / NBLOCKS)   // 4 maps per block

typedef float f32x2 __attribute__((ext_vector_type(2)));

// m = fmax(m, dpp_select(m)); invalid-source / masked-row lanes keep m
// (identity under max).
template <int CTRL, int ROW_MASK>
__device__ __forceinline__ float dpp_max(float m) {
    int t = __builtin_amdgcn_update_dpp(__float_as_int(m), __float_as_int(m),
                                        CTRL, ROW_MASK, 0xF, false);
    return fmaxf(m, __int_as_float(t));
}

__global__ __launch_bounds__(512, 8) void
TopLeftPool_54357106098212_kernel(const float* __restrict__ x,
                                  float* __restrict__ out) {
    __shared__ f32x2 totals[2][NWAVES][64];

    const int w    = (int)(threadIdx.x >> 6);   // wave id = segment id
    const int lane = (int)(threadIdx.x & 63);

    // Fixed per-thread offset within a map (reversed column mapping:
    // lane l covers columns {126-2l, 127-2l}).
    const size_t laneOff = (size_t)(w * SEG) * W + (size_t)(126 - 2 * lane);

    for (int mi = 0; mi < MPB; ++mi) {
        const int map = (int)blockIdx.x + mi * NBLOCKS;
        const size_t mapBase = (size_t)map * (W * W) + laneOff;
        const float* __restrict__ xp = x + mapBase;
        float* __restrict__ op = out + mapBase;

        // Phase 1a: issue every row load in the segment (descending row
        // order, matching consumption order -> incremental vmcnt waits).
        f32x2 v[SEG];
        #pragma unroll
        for (int i = SEG - 1; i >= 0; --i)
            v[i] = *reinterpret_cast<const f32x2*>(xp + (size_t)i * W);

        // Phase 1b: bottom-up segment-local scan, in place.
        float cx = -INFINITY, cy = -INFINITY;
        #pragma unroll
        for (int i = SEG - 1; i >= 0; --i) {
            const float a  = v[i].x;          // col 126-2l
            const float b  = v[i].y;          // col 127-2l
            const float lm = fmaxf(a, b);

            // Exclusive-prefix input: lanemax from lane-1 (lane 0 -> -inf).
            int sh = __builtin_amdgcn_update_dpp(
                __float_as_int(lm), __float_as_int(lm), 0x138 /*wave_shr:1*/,
                0xF, 0xF, false);
            float e = (lane == 0) ? -INFINITY : __int_as_float(sh);

            // Inclusive prefix-max scan over 64 lanes (GFX9 DPP sequence).
            e = dpp_max<0x111, 0xF>(e);   // row_shr:1
            e = dpp_max<0x112, 0xF>(e);   // row_shr:2
            e = dpp_max<0x114, 0xF>(e);   // row_shr:4
            e = dpp_max<0x118, 0xF>(e);   // row_shr:8
            e = dpp_max<0x142, 0xA>(e);   // row_bcast15 -> lanes 16-31, 48-63
            e = dpp_max<0x143, 0xC>(e);   // row_bcast31 -> lanes 32-63

            // Row-suffix values at this lane's two columns:
            //   col 127-2l: max(b, e);  col 126-2l: max(a, b, e) = max(lm, e).
            cx = fmaxf(cx, fmaxf(lm, e));
            cy = fmaxf(cy, fmaxf(b, e));
            v[i].x = cx;
            v[i].y = cy;
        }

        // Phase 2: exchange per-column segment totals (ping-pong buffer,
        // one barrier per map); fold segments below.
        const int p = mi & 1;
        totals[p][w][lane] = (f32x2){cx, cy};
        __syncthreads();

        float fx = -INFINITY, fy = -INFINITY;
        for (int w2 = w + 1; w2 < NWAVES; ++w2) {   // wave-uniform trip count
            const f32x2 t = totals[p][w2][lane];
            fx = fmaxf(fx, t.x);
            fy = fmaxf(fy, t.y);
        }

        // Phase 3: fold and stream out, non-temporal (keep input L3-resident).
        #pragma unroll
        for (int i = 0; i < SEG; ++i) {
            f32x2 o;
            o.x = fmaxf(v[i].x, fx);
            o.y = fmaxf(v[i].y, fy);
            __builtin_nontemporal_store(
                o, reinterpret_cast<f32x2*>(op + (size_t)i * W));
        }
    }
}

extern "C" void kernel_launch(void* const* d_in, const int* in_sizes, int n_in,
                              void* d_out, int out_size, void* d_ws, size_t ws_size,
                              hipStream_t stream) {
    (void)in_sizes; (void)n_in; (void)out_size; (void)d_ws; (void)ws_size;
    const float* x = (const float*)d_in[0];
    float* out = (float*)d_out;

    // Persistent: 1024 blocks (4/CU, all resident), 4 maps per block.
    dim3 grid(NBLOCKS);
    dim3 block(64 * NWAVES);
    hipLaunchKernelGGL(TopLeftPool_54357106098212_kernel, grid, block, 0, stream,
                       x, out);
}